// Round 1
// baseline (644.390 us; speedup 1.0000x reference)
//
#include <hip/hip_runtime.h>
#include <hip/hip_bf16.h>

typedef __bf16 bf16;
typedef __bf16 bf16x4 __attribute__((ext_vector_type(4)));
typedef __bf16 bf16x8 __attribute__((ext_vector_type(8)));
typedef float floatx4 __attribute__((ext_vector_type(4)));
typedef float float4v __attribute__((ext_vector_type(4)));

#define MFMA16(a, b, c) __builtin_amdgcn_mfma_f32_16x16x32_bf16(a, b, c, 0, 0, 0)

constexpr int B_ = 2, S_ = 2048, DIM_ = 1024, H_ = 16, HD_ = 64;
constexpr float SCALE_ = 0.125f;   // HD^-0.5
constexpr float EPS_ = 1e-8f;

// ---------------------------------------------------------------- helpers
__device__ __forceinline__ void gload_lds16(const bf16* g, bf16* l) {
    __builtin_amdgcn_global_load_lds(
        (const __attribute__((address_space(1))) void*)g,
        (__attribute__((address_space(3))) void*)l, 16, 0, 0);
}

// ---------------------------------------------------------------- f32 -> bf16
__global__ __launch_bounds__(256) void cvt_kernel(const float* __restrict__ in,
                                                  bf16* __restrict__ out, int n4) {
    int i = blockIdx.x * 256 + threadIdx.x;
    if (i >= n4) return;
    float4v v = ((const float4v*)in)[i];
    bf16x4 o;
    o[0] = (bf16)v[0]; o[1] = (bf16)v[1]; o[2] = (bf16)v[2]; o[3] = (bf16)v[3];
    ((bf16x4*)out)[i] = o;
}

// ---------------------------------------------------------------- GEMM C = A(MxK) * B(NxK)^T
// A,B bf16 row-major; C f32 (opt +bias) or bf16.  M,N,K multiples of 128/128/64.
template<int OUTF32, int BIASED>
__global__ __launch_bounds__(256) void gemm_bt(const bf16* __restrict__ A,
                                               const bf16* __restrict__ B,
                                               void* __restrict__ Cp,
                                               const float* __restrict__ bias,
                                               int M, int N, int K) {
    __shared__ bf16 As[128 * 64];
    __shared__ bf16 Bs[128 * 64];
    const int lane = threadIdx.x & 63, wid = threadIdx.x >> 6;
    const int colL = lane & 15, grp = lane >> 4;
    const int bm = blockIdx.y * 128, bn = blockIdx.x * 128;
    const int wr = wid >> 1, wc = wid & 1;

    floatx4 acc[4][4];
#pragma unroll
    for (int m = 0; m < 4; ++m)
#pragma unroll
        for (int n = 0; n < 4; ++n) acc[m][n] = (floatx4){0.f, 0.f, 0.f, 0.f};

    for (int k0 = 0; k0 < K; k0 += 64) {
#pragma unroll
        for (int i = 0; i < 4; ++i) {
            int c = wid * 256 + i * 64 + lane;     // 16B chunk id, linear in lane
            int row = c >> 3, sub = c & 7;
            gload_lds16(A + (size_t)(bm + row) * K + k0 + sub * 8,
                        &As[(wid * 256 + i * 64) * 8]);
            gload_lds16(B + (size_t)(bn + row) * K + k0 + sub * 8,
                        &Bs[(wid * 256 + i * 64) * 8]);
        }
        __syncthreads();
#pragma unroll
        for (int ks = 0; ks < 2; ++ks) {
            bf16x8 af[4], bfr[4];
#pragma unroll
            for (int m = 0; m < 4; ++m)
                af[m] = *(const bf16x8*)(&As[(wr * 64 + m * 16 + colL) * 64 + ks * 32 + grp * 8]);
#pragma unroll
            for (int n = 0; n < 4; ++n)
                bfr[n] = *(const bf16x8*)(&Bs[(wc * 64 + n * 16 + colL) * 64 + ks * 32 + grp * 8]);
#pragma unroll
            for (int m = 0; m < 4; ++m)
#pragma unroll
                for (int n = 0; n < 4; ++n)
                    acc[m][n] = MFMA16(af[m], bfr[n], acc[m][n]);
        }
        __syncthreads();
    }

#pragma unroll
    for (int m = 0; m < 4; ++m)
#pragma unroll
        for (int n = 0; n < 4; ++n)
#pragma unroll
            for (int r = 0; r < 4; ++r) {
                int row = bm + wr * 64 + m * 16 + grp * 4 + r;
                int col = bn + wc * 64 + n * 16 + colL;
                float v = acc[m][n][r];
                if (BIASED) v += bias[col];
                if (OUTF32) ((float*)Cp)[(size_t)row * N + col] = v;
                else        ((bf16*)Cp)[(size_t)row * N + col] = (bf16)v;
            }
}

// ---------------------------------------------------------------- RoPE (+scale), (B,S,DIM-slice) -> (B,H,S,HD)
__global__ __launch_bounds__(256) void rope_kernel(const bf16* __restrict__ in,
                                                   const float* __restrict__ fr,
                                                   bf16* __restrict__ out,
                                                   int in_ld, float scale) {
    int tid = blockIdx.x * 256 + threadIdx.x;   // < B*S*H*8 = 524288
    int j = tid & 7, h = (tid >> 3) & 15, s = (tid >> 7) & 2047, b = tid >> 18;
    bf16x8 x = *(const bf16x8*)(in + (size_t)(b * 2048 + s) * in_ld + h * 64 + j * 8);
    const float* f = fr + (size_t)(b * 2048 + s) * 64 + j * 4;
    bf16x8 o;
#pragma unroll
    for (int i = 0; i < 4; ++i) {
        float c = f[i], sn = f[32 + i];   // fr[.., p] / fr[.., 32+p], p = j*4+i
        float x0 = (float)x[2 * i], x1 = (float)x[2 * i + 1];
        o[2 * i]     = (bf16)((x0 * c - x1 * sn) * scale);
        o[2 * i + 1] = (bf16)((x0 * sn + x1 * c) * scale);
    }
    *(bf16x8*)(out + ((size_t)(b * 16 + h) * 2048 + s) * 64 + j * 8) = o;
}

// ---------------------------------------------------------------- V transpose: KVp(B,S,2048) v-part -> Vt(B,H,HD,S)
__global__ __launch_bounds__(256) void vtrans_kernel(const bf16* __restrict__ KVp,
                                                     bf16* __restrict__ Vt) {
    int bid = blockIdx.x;               // b*512 + h*32 + sb
    int sb = bid & 31, h = (bid >> 5) & 15, b = bid >> 9;
    __shared__ bf16 tile[64][66];       // [s][d], pad to 66 (odd dword stride)
    int tid = threadIdx.x;
#pragma unroll
    for (int i = 0; i < 2; ++i) {
        int c = tid + i * 256;          // 512 chunks of 8
        int row = c >> 3, sub = c & 7;
        bf16x8 x = *(const bf16x8*)(KVp + (size_t)(b * 2048 + sb * 64 + row) * 2048
                                    + 1024 + h * 64 + sub * 8);
#pragma unroll
        for (int k = 0; k < 8; ++k) tile[row][sub * 8 + k] = x[k];
    }
    __syncthreads();
#pragma unroll
    for (int i = 0; i < 2; ++i) {
        int c = tid + i * 256;
        int drow = c >> 3, sub = c & 7;
        bf16x8 o;
#pragma unroll
        for (int k = 0; k < 8; ++k) o[k] = tile[sub * 8 + k][drow];
        *(bf16x8*)(Vt + ((size_t)(b * 16 + h) * 64 + drow) * 2048 + sb * 64 + sub * 8) = o;
    }
}

// ---------------------------------------------------------------- fused attention
// Qr (B,H,S,64) bf16 (scale folded), Kr (B,H,S,64) bf16, Vt (B,H,64,S) bf16
// mask (B,1,S,S) f32, prior (B,S,S) f32 -> attn_out (B,H,S,S) f32, O (B,S,DIM) bf16
__global__ __launch_bounds__(256) void attn_kernel(const bf16* __restrict__ Qr,
                                                   const bf16* __restrict__ Kr,
                                                   const bf16* __restrict__ Vt,
                                                   const float* __restrict__ mask,
                                                   const float* __restrict__ prior,
                                                   float* __restrict__ attn_out,
                                                   bf16* __restrict__ O) {
    __shared__ bf16 t_lds[4][16][64];
    const int lane = threadIdx.x & 63, wid = threadIdx.x >> 6;
    const int bidx = blockIdx.x;              // b*512 + h*32 + qb
    const int qb = bidx & 31, h = (bidx >> 5) & 15, b = bidx >> 9;
    const int q0 = qb * 64 + wid * 16;        // this wave's 16 q rows
    const int colL = lane & 15, grp = lane >> 4;

    const bf16* Qbase = Qr + ((size_t)(b * H_ + h) * S_ + q0) * HD_;
    const bf16* Kbase = Kr + (size_t)(b * H_ + h) * S_ * HD_;
    const bf16* Vbase = Vt + (size_t)(b * H_ + h) * HD_ * S_;
    const float* Mbase = mask + ((size_t)b * S_ + q0) * S_;
    const float* Pbase = prior + ((size_t)b * S_ + q0) * S_;

    bf16x8 qf0 = *(const bf16x8*)(Qbase + (size_t)colL * HD_ + grp * 8);
    bf16x8 qf1 = *(const bf16x8*)(Qbase + (size_t)colL * HD_ + 32 + grp * 8);

    float m_run[4], U[4];
    floatx4 o_acc[4];
#pragma unroll
    for (int r = 0; r < 4; ++r) { m_run[r] = -1e30f; U[r] = 0.f; }
#pragma unroll
    for (int d = 0; d < 4; ++d) o_acc[d] = (floatx4){0.f, 0.f, 0.f, 0.f};

    // ---------------- pass 1: online m, U = sum(e*p), O_u = sum(e*p*V)
    for (int kt = 0; kt < S_ / 64; ++kt) {
        const int k0 = kt * 64;
        floatx4 s[4];
#pragma unroll
        for (int ct = 0; ct < 4; ++ct) {
            const bf16* kb = Kbase + (size_t)(k0 + ct * 16 + colL) * HD_ + grp * 8;
            floatx4 c = (floatx4){0.f, 0.f, 0.f, 0.f};
            c = MFMA16(qf0, *(const bf16x8*)kb, c);
            c = MFMA16(qf1, *(const bf16x8*)(kb + 32), c);
            s[ct] = c;
        }
        float lv[4][4], mt[4];
#pragma unroll
        for (int r = 0; r < 4; ++r) mt[r] = -1e30f;
#pragma unroll
        for (int ct = 0; ct < 4; ++ct)
#pragma unroll
            for (int r = 0; r < 4; ++r) {
                float x = s[ct][r] + Mbase[(size_t)(grp * 4 + r) * S_ + k0 + ct * 16 + colL];
                lv[ct][r] = x;
                mt[r] = fmaxf(mt[r], x);
            }
#pragma unroll
        for (int off = 1; off < 16; off <<= 1)
#pragma unroll
            for (int r = 0; r < 4; ++r) mt[r] = fmaxf(mt[r], __shfl_xor(mt[r], off, 64));
        float alpha[4];
#pragma unroll
        for (int r = 0; r < 4; ++r) {
            float mn = fmaxf(m_run[r], mt[r]);
            alpha[r] = __expf(m_run[r] - mn);
            m_run[r] = mn;
        }
        float Uadd[4] = {0.f, 0.f, 0.f, 0.f};
        float tq[4][4];
#pragma unroll
        for (int ct = 0; ct < 4; ++ct)
#pragma unroll
            for (int r = 0; r < 4; ++r) {
                float e = __expf(lv[ct][r] - m_run[r]);
                float p = Pbase[(size_t)(grp * 4 + r) * S_ + k0 + ct * 16 + colL];
                float tv = e * fmaxf(p, EPS_);
                tq[ct][r] = tv;
                Uadd[r] += tv;
            }
#pragma unroll
        for (int off = 1; off < 16; off <<= 1)
#pragma unroll
            for (int r = 0; r < 4; ++r) Uadd[r] += __shfl_xor(Uadd[r], off, 64);
#pragma unroll
        for (int r = 0; r < 4; ++r) U[r] = U[r] * alpha[r] + Uadd[r];
#pragma unroll
        for (int d = 0; d < 4; ++d)
#pragma unroll
            for (int r = 0; r < 4; ++r) o_acc[d][r] *= alpha[r];
        // P tile -> LDS (re-layout to A-fragment order), wave-private region
#pragma unroll
        for (int ct = 0; ct < 4; ++ct)
#pragma unroll
            for (int r = 0; r < 4; ++r)
                t_lds[wid][grp * 4 + r][ct * 16 + colL] = (bf16)tq[ct][r];
        // PV
#pragma unroll
        for (int ks = 0; ks < 2; ++ks) {
            bf16x8 pa = *(const bf16x8*)(&t_lds[wid][colL][ks * 32 + grp * 8]);
#pragma unroll
            for (int d = 0; d < 4; ++d) {
                const bf16* vb = Vbase + (size_t)(d * 16 + colL) * S_ + k0 + ks * 32 + grp * 8;
                o_acc[d] = MFMA16(pa, *(const bf16x8*)vb, o_acc[d]);
            }
        }
    }

    float invU[4];
#pragma unroll
    for (int r = 0; r < 4; ++r) invU[r] = 1.0f / U[r];
#pragma unroll
    for (int d = 0; d < 4; ++d)
#pragma unroll
        for (int r = 0; r < 4; ++r) {
            int q = q0 + grp * 4 + r;
            O[((size_t)b * S_ + q) * DIM_ + h * HD_ + d * 16 + colL] =
                (bf16)(o_acc[d][r] * invU[r]);
        }

    // ---------------- pass 2: recompute logits, write attn = e*p/U
    float* Abase = attn_out + ((size_t)(b * H_ + h) * S_ + q0) * S_;
    for (int kt = 0; kt < S_ / 64; ++kt) {
        const int k0 = kt * 64;
        floatx4 s[4];
#pragma unroll
        for (int ct = 0; ct < 4; ++ct) {
            const bf16* kb = Kbase + (size_t)(k0 + ct * 16 + colL) * HD_ + grp * 8;
            floatx4 c = (floatx4){0.f, 0.f, 0.f, 0.f};
            c = MFMA16(qf0, *(const bf16x8*)kb, c);
            c = MFMA16(qf1, *(const bf16x8*)(kb + 32), c);
            s[ct] = c;
        }
#pragma unroll
        for (int ct = 0; ct < 4; ++ct)
#pragma unroll
            for (int r = 0; r < 4; ++r) {
                size_t ro = (size_t)(grp * 4 + r) * S_ + k0 + ct * 16 + colL;
                float x = s[ct][r] + Mbase[ro];
                float e = __expf(x - m_run[r]);
                float p = Pbase[ro];
                Abase[ro] = e * fmaxf(p, EPS_) * invU[r];
            }
    }
}

// ---------------------------------------------------------------- launch
extern "C" void kernel_launch(void* const* d_in, const int* in_sizes, int n_in,
                              void* d_out, int out_size, void* d_ws, size_t ws_size,
                              hipStream_t stream) {
    const float* q_x   = (const float*)d_in[0];
    const float* kv_x  = (const float*)d_in[1];
    const float* q_fr  = (const float*)d_in[2];
    const float* k_fr  = (const float*)d_in[3];
    const float* maskp = (const float*)d_in[4];
    const float* prior = (const float*)d_in[5];
    const float* Wq    = (const float*)d_in[6];
    const float* Wkv   = (const float*)d_in[7];
    const float* Wproj = (const float*)d_in[8];
    const float* bproj = (const float*)d_in[9];

    float* out_x    = (float*)d_out;                       // (B,S,DIM)
    float* out_attn = out_x + (size_t)B_ * S_ * DIM_;      // (B,H,S,S)

    char* w = (char*)d_ws;
    bf16* qx_b  = (bf16*)(w + (size_t)0);          //  8 MiB
    bf16* kvx_b = (bf16*)(w + ((size_t)8  << 20)); //  8 MiB
    bf16* wq_b  = (bf16*)(w + ((size_t)16 << 20)); //  2 MiB
    bf16* wkv_b = (bf16*)(w + ((size_t)18 << 20)); //  4 MiB
    bf16* wpj_b = (bf16*)(w + ((size_t)22 << 20)); //  2 MiB
    bf16* qp    = (bf16*)(w + ((size_t)24 << 20)); //  8 MiB  (B,S,DIM)
    bf16* kvp   = (bf16*)(w + ((size_t)32 << 20)); // 16 MiB  (B,S,2*DIM)
    bf16* qr    = (bf16*)(w + ((size_t)48 << 20)); //  8 MiB  (B,H,S,HD)
    bf16* kr    = (bf16*)(w + ((size_t)56 << 20)); //  8 MiB
    bf16* vt    = (bf16*)(w + ((size_t)64 << 20)); //  8 MiB  (B,H,HD,S)
    bf16* ob    = (bf16*)(w + ((size_t)72 << 20)); //  8 MiB  (B,S,DIM)

    // f32 -> bf16 conversions
    cvt_kernel<<<4096, 256, 0, stream>>>(q_x,   qx_b,  1048576);
    cvt_kernel<<<4096, 256, 0, stream>>>(kv_x,  kvx_b, 1048576);
    cvt_kernel<<<1024, 256, 0, stream>>>(Wq,    wq_b,   262144);
    cvt_kernel<<<2048, 256, 0, stream>>>(Wkv,   wkv_b,  524288);
    cvt_kernel<<<1024, 256, 0, stream>>>(Wproj, wpj_b,  262144);

    // projections
    gemm_bt<0, 0><<<dim3(8, 32),  256, 0, stream>>>(qx_b,  wq_b,  qp,  nullptr, 4096, 1024, 1024);
    gemm_bt<0, 0><<<dim3(16, 32), 256, 0, stream>>>(kvx_b, wkv_b, kvp, nullptr, 4096, 2048, 1024);

    // RoPE + layout
    rope_kernel<<<2048, 256, 0, stream>>>(qp,  q_fr, qr, 1024, SCALE_);
    rope_kernel<<<2048, 256, 0, stream>>>(kvp, k_fr, kr, 2048, 1.0f);
    vtrans_kernel<<<1024, 256, 0, stream>>>(kvp, vt);

    // fused attention (writes attn + O)
    attn_kernel<<<1024, 256, 0, stream>>>(qr, kr, vt, maskp, prior, out_attn, ob);

    // output projection
    gemm_bt<1, 1><<<dim3(8, 32), 256, 0, stream>>>(ob, wpj_b, out_x, bproj, 4096, 1024, 1024);
}